// Round 15
// baseline (141.427 us; speedup 1.0000x reference)
//
#include <hip/hip_runtime.h>
#include <hip/hip_bf16.h>

typedef unsigned short u16;
typedef unsigned int   u32;

using bf16x8 = __attribute__((ext_vector_type(8))) short;  // 8 bf16 in 4 VGPRs
using f32x4  = __attribute__((ext_vector_type(4))) float;  // MFMA accumulator

#define NB 32
#define NP 1024
#define ND 256

__device__ __forceinline__ u16 f2bf(float x){
  u32 u = __float_as_uint(x);
  u += 0x7FFFu + ((u >> 16) & 1u);   // round-to-nearest-even
  return (u16)(u >> 16);
}

__device__ __forceinline__ float bf2f(u16 x){
  return __uint_as_float((u32)x << 16);
}

__device__ __forceinline__ void glds16(const void* g, void* l){
  __builtin_amdgcn_global_load_lds((const __attribute__((address_space(1))) void*)g,
                                   (__attribute__((address_space(3))) void*)l, 16, 0, 0);
}

// ---------------- prep 1: Pbf = bf16(P), sbv[row] = P[row,:] . wb ----------------
__global__ void prep_rows(const float* __restrict__ P, const float* __restrict__ wi,
                          u16* __restrict__ Pbf, float* __restrict__ sbv){
  const int row  = blockIdx.x * 4 + (threadIdx.x >> 6);   // one wave per row
  const int lane = threadIdx.x & 63;
  const float4 p  = *(const float4*)(P  + (size_t)row * ND + lane * 4);
  const float4 wb = *(const float4*)(wi + ND + lane * 4);  // wb = wi[256:512]
  ushort4 pb;
  pb.x = f2bf(p.x); pb.y = f2bf(p.y); pb.z = f2bf(p.z); pb.w = f2bf(p.w);
  *(ushort4*)(Pbf + (size_t)row * ND + lane * 4) = pb;
  float s = p.x*wb.x + p.y*wb.y + p.z*wb.z + p.w*wb.w;
  #pragma unroll
  for (int m = 1; m < 64; m <<= 1) s += __shfl_xor(s, m, 64);
  if (lane == 0) sbv[row] = s;
}

// ------- prep 2: pack W fragment-major: Wp[((t*16+c)*64+lane)*8 + e] -------------
__global__ void prep_w(const float* __restrict__ w1, const float* __restrict__ w2,
                       const float* __restrict__ w3, u16* __restrict__ Wp){
  const int t = blockIdx.x;                       // 0..47
  const float* w = (t < 16) ? w1 : ((t < 32) ? w2 : w3);
  const int tid = threadIdx.x;
  #pragma unroll
  for (int j = 0; j < 4; ++j){
    int item = tid + 256 * j;                     // c*64 + lane
    int c = item >> 6, lane = item & 63;
    int ncol = ((t & 15) << 4) + (lane & 15);
    int k0 = 32 * c + 8 * (lane >> 4);
    u16 tmp[8];
    #pragma unroll
    for (int e = 0; e < 8; ++e) tmp[e] = f2bf(w[(size_t)(k0 + e) * 256 + ncol]);
    *(uint4*)(Wp + ((size_t)(t * 16 + c) * 64 + lane) * 8) = *(uint4*)tmp;
  }
}

// ---------------- prep 3: PbfT[b][d][j] = Pbf[b][j][d] (64x64 LDS tiles) ---------
__global__ void transpose_p(const u16* __restrict__ Pbf, u16* __restrict__ PbfT){
  const int b = blockIdx.z, jt = blockIdx.x, dt = blockIdx.y;
  __shared__ u16 T[64][72];
  const int tid = threadIdx.x;
  #pragma unroll
  for (int it = 0; it < 2; ++it){
    int cc = tid + 256 * it;               // 0..511: 64 j-rows x 8 chunks
    int j = cc >> 3, c8 = cc & 7;
    uint4 v = *(const uint4*)(Pbf + ((size_t)b * NP + jt * 64 + j) * ND + dt * 64 + c8 * 8);
    *(uint4*)&T[j][c8 * 8] = v;
  }
  __syncthreads();
  #pragma unroll
  for (int it = 0; it < 2; ++it){
    int cc = tid + 256 * it;               // 64 d-rows x 8 chunks
    int d = cc >> 3, c8 = cc & 7;
    u16 tmp[8];
    #pragma unroll
    for (int k = 0; k < 8; ++k) tmp[k] = T[c8 * 8 + k][d];
    *(uint4*)(PbfT + ((size_t)b * ND + dt * 64 + d) * NP + jt * 64 + c8 * 8) = *(uint4*)tmp;
  }
}

// -------- attention: r14 structure + SPLIT-K over the key range ------------------
// r14 evidence: LDS 37.9KB gives CAPACITY 4 blocks/CU but grid 512 = 2/CU ->
// occupancy stuck at 21% and the per-tile barrier+DMA stall (~6.5K cyc/tile vs
// <2K of real work) stays uncovered. Split-K: each block handles HALF the keys
// (16 tiles), grid 1024 -> 4 resident blocks/CU = 4 independent barrier domains.
// Staged bytes unchanged. Each half writes normalized partial O (bf16) + (m,l)
// per row; combine_kernel merges. Fallback (ws too small): single pass, r14-exact.
// Layouts unchanged from r14 (bank-validated): K j*512+16*(ck^(j&7));
// V d*64+16*(kc^((d>>1)&3)); Sp[4][16][40].
__launch_bounds__(256, 3)
__global__ void attn_kernel(const float* __restrict__ P, const float* __restrict__ wi,
                            const u16* __restrict__ Pbf, const u16* __restrict__ PbfT,
                            const float* __restrict__ sbv,
                            u16* __restrict__ ob0, u16* __restrict__ ob1,
                            float* __restrict__ mlb, int splitk){
  int p2, kt0, nkt;
  u16* obuf;
  float* mlo;
  if (splitk){
    const int half = blockIdx.x >> 9;             // 0..1
    p2  = blockIdx.x & 511;
    kt0 = half * 16; nkt = 16;
    obuf = half ? ob1 : ob0;
    mlo  = mlb + (size_t)half * 2 * (NB * NP);
  } else {
    p2 = blockIdx.x; kt0 = 0; nkt = 32;
    obuf = ob0; mlo = nullptr;
  }
  const int bid  = ((p2 & 7) << 6) | (p2 >> 3);   // 64 consecutive bids per XCD
  const int b    = bid >> 4;
  const int q0   = (bid & 15) << 6;
  const int tid  = threadIdx.x;
  const int wave = tid >> 6, lane = tid & 63, lo = lane & 15, hi = lane >> 4;

  __shared__ __align__(16) u16 KtA[32 * 256];     // 16 KB
  __shared__ __align__(16) u16 VtA[256 * 32];     // 16 KB
  __shared__ __align__(16) u16 Sp[4][16][40];     // 5 KB
  char* KtB = (char*)KtA;
  char* VtB = (char*)VtA;

  // ---- Q fragments (A-operand): q = P * wc, bf16, in regs ----
  bf16x8 qf[8];
  {
    const int qrow = q0 + wave * 16 + lo;
    const float* prow = P  + ((size_t)b * NP + qrow) * ND;
    const float* wcp  = wi + 512;
    #pragma unroll
    for (int c = 0; c < 8; ++c){
      const int d0 = 32 * c + 8 * hi;
      float4 a  = *(const float4*)(prow + d0);
      float4 a2 = *(const float4*)(prow + d0 + 4);
      float4 wa  = *(const float4*)(wcp + d0);
      float4 wa2 = *(const float4*)(wcp + d0 + 4);
      bf16x8 q;
      q[0]=(short)f2bf(a.x*wa.x);  q[1]=(short)f2bf(a.y*wa.y);
      q[2]=(short)f2bf(a.z*wa.z);  q[3]=(short)f2bf(a.w*wa.w);
      q[4]=(short)f2bf(a2.x*wa2.x); q[5]=(short)f2bf(a2.y*wa2.y);
      q[6]=(short)f2bf(a2.z*wa2.z); q[7]=(short)f2bf(a2.w*wa2.w);
      qf[c] = q;
    }
  }

  f32x4 of[16];
  #pragma unroll
  for (int t = 0; t < 16; ++t) of[t] = (f32x4){0.f,0.f,0.f,0.f};
  float mx[4] = {-1e30f,-1e30f,-1e30f,-1e30f};
  float ls[4] = {0.f,0.f,0.f,0.f};

  const u16* kslab = Pbf  + (size_t)b * NP * ND;   // row-major [j][d]
  const u16* vslab = PbfT + (size_t)b * ND * NP;   // d-major  [d][j]

  auto stageK = [&](int kt){
    const int kbase = kt * 32;
    #pragma unroll
    for (int it = 0; it < 4; ++it){
      int off = it * 4096 + tid * 16;             // linear LDS dest byte
      int j   = off >> 9;                          // key row 0..31
      int ck  = ((off >> 4) & 31) ^ (j & 7);
      glds16((const char*)(kslab + (size_t)(kbase + j) * ND + ck * 8), KtB + off);
    }
  };
  auto stageV = [&](int kt){
    const int kbase = kt * 32;
    #pragma unroll
    for (int it = 0; it < 4; ++it){
      int off = it * 4096 + tid * 16;
      int pidx = off >> 4;                         // 16B unit index
      int d   = pidx >> 2;                         // feature row 0..255
      int u   = pidx & 3;
      int kc  = u ^ ((d >> 1) & 3);
      glds16((const char*)(vslab + (size_t)d * NP + kbase + kc * 8), VtB + off);
    }
  };

  float sbc[2], sbn[2];
  stageK(kt0);
  stageV(kt0);
  #pragma unroll
  for (int nt = 0; nt < 2; ++nt) sbc[nt] = sbv[(size_t)b * NP + kt0 * 32 + nt * 16 + lo];
  __syncthreads();                                 // drain: first K,V valid

  for (int kk = 0; kk < nkt; ++kk){
    const int kt = kt0 + kk;
    // ---- S = Q K^T (2 col-tiles; V(kt) glds drained by this iter's entry) ----
    f32x4 s[2];
    #pragma unroll
    for (int nt = 0; nt < 2; ++nt){
      f32x4 acc = (f32x4){0.f,0.f,0.f,0.f};
      #pragma unroll
      for (int c = 0; c < 8; ++c){
        int j  = nt * 16 + lo;
        int ad = j * 512 + (((4 * c + hi) ^ (j & 7)) << 4);
        bf16x8 kf = *(const bf16x8*)(KtB + ad);
        acc = __builtin_amdgcn_mfma_f32_16x16x32_bf16(qf[c], kf, acc, 0, 0, 0);
      }
      s[nt] = acc;
      float sv = sbc[nt];
      #pragma unroll
      for (int r = 0; r < 4; ++r) s[nt][r] += sv;
    }

    __syncthreads();                  // barrier1: all waves done reading Kt
    if (kk < nkt - 1) stageK(kt + 1); // in flight across softmax+PV; drains at b2

    // ---- deferred online softmax ----
    float md = -1e30f;
    #pragma unroll
    for (int nt = 0; nt < 2; ++nt)
      #pragma unroll
      for (int r = 0; r < 4; ++r) md = fmaxf(md, s[nt][r] - mx[r]);
    if (!__all(md <= 8.f)){
      // slow path: proper row maxima + rescale (first tile, rare after)
      float scale[4];
      #pragma unroll
      for (int r = 0; r < 4; ++r){
        float v = fmaxf(s[0][r], s[1][r]);
        v = fmaxf(v, __shfl_xor(v, 1, 64));
        v = fmaxf(v, __shfl_xor(v, 2, 64));
        v = fmaxf(v, __shfl_xor(v, 4, 64));
        v = fmaxf(v, __shfl_xor(v, 8, 64));
        float mnew = fmaxf(mx[r], v);
        scale[r] = __expf(mx[r] - mnew);
        mx[r] = mnew;
        ls[r] *= scale[r];
      }
      #pragma unroll
      for (int t = 0; t < 16; ++t)
        #pragma unroll
        for (int r = 0; r < 4; ++r) of[t][r] *= scale[r];
    }
    // common path: exp, per-lane partial sums, repack (p bounded by e^8)
    #pragma unroll
    for (int nt = 0; nt < 2; ++nt)
      #pragma unroll
      for (int r = 0; r < 4; ++r){
        float pv = __expf(s[nt][r] - mx[r]);
        ls[r] += pv;
        Sp[wave][4 * hi + r][16 * nt + lo] = f2bf(pv);
      }

    // ---- O += P V (single K=32 MFMA per d-tile; Sp is within-wave) ----
    {
      bf16x8 pa = *(const bf16x8*)&Sp[wave][lo][8 * hi];
      #pragma unroll
      for (int t = 0; t < 16; ++t){
        int d  = 16 * t + lo;
        int ad = d * 64 + ((hi ^ ((d >> 1) & 3)) << 4);
        bf16x8 vb = *(const bf16x8*)(VtB + ad);
        of[t] = __builtin_amdgcn_mfma_f32_16x16x32_bf16(pa, vb, of[t], 0, 0, 0);
      }
    }

    __syncthreads();                  // barrier2: Vt reads done; drains K(t+1)
    if (kk < nkt - 1){
      stageV(kt + 1);                 // in flight across next QK^T; drains at b1
      #pragma unroll
      for (int nt = 0; nt < 2; ++nt)
        sbn[nt] = sbv[(size_t)b * NP + (kt + 1) * 32 + nt * 16 + lo];
      sbc[0] = sbn[0]; sbc[1] = sbn[1];
    }
  }

  // ---- epilogue: cross-lane ls reduce, O /= l, store bf16 (+ m,l if split) ----
  #pragma unroll
  for (int r = 0; r < 4; ++r){
    ls[r] += __shfl_xor(ls[r], 1, 64);
    ls[r] += __shfl_xor(ls[r], 2, 64);
    ls[r] += __shfl_xor(ls[r], 4, 64);
    ls[r] += __shfl_xor(ls[r], 8, 64);
  }
  const int qrow = q0 + wave * 16;
  #pragma unroll
  for (int t = 0; t < 16; ++t){
    #pragma unroll
    for (int r = 0; r < 4; ++r){
      float o = of[t][r] / ls[r];
      obuf[((size_t)b * NP + qrow + 4 * hi + r) * ND + 16 * t + lo] = f2bf(o);
    }
  }
  if (mlo && lo == 0){
    #pragma unroll
    for (int r = 0; r < 4; ++r){
      size_t rowi = (size_t)b * NP + qrow + 4 * hi + r;
      mlo[2 * rowi]     = mx[r];
      mlo[2 * rowi + 1] = ls[r];
    }
  }
}

// -------- combine: O = (e^{m1-m} l1 O1 + e^{m2-m} l2 O2) / (w1 + w2) -------------
__global__ void combine_kernel(const u16* __restrict__ o2buf,
                               const float* __restrict__ mlb,
                               u16* __restrict__ attnb){
  const int tid = threadIdx.x;
  const size_t row = (size_t)blockIdx.x * 8 + (tid >> 5);  // 0..32767
  const int d0 = (tid & 31) * 8;
  const float m1 = mlb[2 * row],                l1 = mlb[2 * row + 1];
  const float m2 = mlb[2 * (NB * NP) + 2 * row], l2 = mlb[2 * (NB * NP) + 2 * row + 1];
  const float m  = fmaxf(m1, m2);
  const float w1 = __expf(m1 - m) * l1;
  const float w2 = __expf(m2 - m) * l2;
  const float inv = 1.f / (w1 + w2);
  const float a1 = w1 * inv, a2 = w2 * inv;
  uint4 v1 = *(const uint4*)(attnb + row * ND + d0);
  uint4 v2 = *(const uint4*)(o2buf + row * ND + d0);
  const u16* p1 = (const u16*)&v1;
  const u16* p2 = (const u16*)&v2;
  u16 outv[8];
  #pragma unroll
  for (int e = 0; e < 8; ++e)
    outv[e] = f2bf(a1 * bf2f(p1[e]) + a2 * bf2f(p2[e]));
  *(uint4*)(attnb + row * ND + d0) = *(uint4*)outv;
}

// ---------------- MLP: proper GEMM, M-tile 128, fused gate epilogue --------------
// NOTE: acc[3][8] = 96 VGPRs of accumulator. __launch_bounds__ min-waves MUST stay
// at 2 (VGPR budget 256): round-5's (256,4) capped the allocator at 64 VGPR and
// spilled all accumulators to scratch (WRITE_SIZE 33 -> 325 MB, 18 -> 136 us).
__launch_bounds__(256, 2)
__global__ void mlp_kernel(const u16* __restrict__ Pbf, const u16* __restrict__ attnb,
                           const u16* __restrict__ Wp,
                           const float* __restrict__ b1, const float* __restrict__ b2,
                           const float* __restrict__ b3, float* __restrict__ out){
  const int p    = blockIdx.x;
  const int swz  = ((p & 7) << 7) | (p >> 3);     // XCD-chunked
  const int mt   = swz >> 2, cg = swz & 3;
  const int tid  = threadIdx.x;
  const int wave = tid >> 6, lane = tid & 63, lo = lane & 15, hi = lane >> 4;
  const int tq   = 4 * cg + wave;
  const int m0   = mt * 128;

  __shared__ __align__(16) u16 Ab[2][128 * 64];   // 2 x 16 KB, swizzled

  f32x4 acc[3][8];
  #pragma unroll
  for (int e = 0; e < 3; ++e)
    #pragma unroll
    for (int m = 0; m < 8; ++m) acc[e][m] = (f32x4){0.f,0.f,0.f,0.f};

  auto stage = [&](int s, int buf){
    const u16* xs = (s < 4) ? (Pbf   + (size_t)m0 * ND + s * 64)
                            : (attnb + (size_t)m0 * ND + (s - 4) * 64);
    char* dst = (char*)Ab[buf];
    #pragma unroll
    for (int it = 0; it < 4; ++it){
      int off = it * 4096 + wave * 1024 + lane * 16;   // physical LDS byte
      int row = off >> 7;                               // 128B per row
      int cl  = (off & 127) ^ ((row & 7) << 4);         // logical byte in row
      glds16((const char*)(xs + (size_t)row * ND) + cl, dst + it * 4096 + wave * 1024);
    }
  };

  stage(0, 0);
  __syncthreads();

  for (int s = 0; s < 8; ++s){
    if (s < 7) stage(s + 1, (s + 1) & 1);
    const char* ab = (const char*)Ab[s & 1];
    #pragma unroll
    for (int cc = 0; cc < 2; ++cc){
      const int c = 2 * s + cc;
      bf16x8 wf[3];
      #pragma unroll
      for (int e = 0; e < 3; ++e)
        wf[e] = *(const bf16x8*)(Wp + ((size_t)((tq + 16 * e) * 16 + c) * 64 + lane) * 8);
      #pragma unroll
      for (int m = 0; m < 8; ++m){
        int row = 16 * m + lo;
        bf16x8 af = *(const bf16x8*)(ab + row * 128 + ((64 * cc + 16 * hi) ^ ((row & 7) << 4)));
        #pragma unroll
        for (int e = 0; e < 3; ++e)
          acc[e][m] = __builtin_amdgcn_mfma_f32_16x16x32_bf16(af, wf[e], acc[e][m], 0, 0, 0);
      }
    }
    __syncthreads();
  }

  // ---- fused gate epilogue ----
  const int d = 16 * tq + lo;
  const float bb1 = b1[d], bb2 = b2[d], bb3 = b3[d];
  #pragma unroll
  for (int m = 0; m < 8; ++m){
    #pragma unroll
    for (int r = 0; r < 4; ++r){
      const int row = m0 + 16 * m + 4 * hi + r;
      float y1 = acc[0][m][r] + bb1;
      float y2 = acc[1][m][r] + bb2;
      float y3 = acc[2][m][r] + bb3;
      float pv = bf2f(Pbf[(size_t)row * ND + d]);
      float e2 = __expf(2.f * y1);
      float z  = (e2 - 1.f) / (e2 + 1.f);          // tanh
      float rr = 1.f / (1.f + __expf(-y2));        // sigmoid
      float ff = 1.f / (1.f + __expf(-y3));        // sigmoid
      out[(size_t)row * ND + d] = rr * pv + ff * z;
    }
  }
}

extern "C" void kernel_launch(void* const* d_in, const int* in_sizes, int n_in,
                              void* d_out, int out_size, void* d_ws, size_t ws_size,
                              hipStream_t stream){
  const float* P  = (const float*)d_in[0];
  const float* wi = (const float*)d_in[1];
  const float* w1 = (const float*)d_in[2];
  const float* w2 = (const float*)d_in[3];
  const float* w3 = (const float*)d_in[4];
  const float* b1 = (const float*)d_in[5];
  const float* b2 = (const float*)d_in[6];
  const float* b3 = (const float*)d_in[7];
  float* out = (float*)d_out;

  char* ws = (char*)d_ws;
  u16*   Pbf   = (u16*)  (ws);                        // 16 MB
  u16*   PbfT  = (u16*)  (ws + (16u << 20));          // 16 MB
  u16*   attnb = (u16*)  (ws + (32u << 20));          // 16 MB (partial-0 in split)
  u16*   Wp    = (u16*)  (ws + (48u << 20));          // 768 KB packed fragments
  float* sbv   = (float*)(ws + (49u << 20));          // 128 KB
  u16*   part1 = (u16*)  (ws + (50u << 20));          // 16 MB (split-K partial-1)
  float* mlb   = (float*)(ws + (66u << 20));          // 512 KB (m,l per row x2)

  const int splitk = (ws_size >= (67ull << 20)) ? 1 : 0;

  prep_rows<<<8192, 256, 0, stream>>>(P, wi, Pbf, sbv);
  prep_w<<<48, 256, 0, stream>>>(w1, w2, w3, Wp);
  transpose_p<<<dim3(16, 4, 32), 256, 0, stream>>>(Pbf, PbfT);
  attn_kernel<<<splitk ? 1024 : 512, 256, 0, stream>>>(P, wi, Pbf, PbfT, sbv,
                                                       attnb, part1, mlb, splitk);
  if (splitk) combine_kernel<<<4096, 256, 0, stream>>>(part1, mlb, attnb);
  mlp_kernel<<<1024, 256, 0, stream>>>(Pbf, attnb, Wp, b1, b2, b3, out);
}

// Round 16
// 112.667 us; speedup vs baseline: 1.2553x; 1.2553x over previous
//
#include <hip/hip_runtime.h>
#include <hip/hip_bf16.h>

typedef unsigned short u16;
typedef unsigned int   u32;

using bf16x8 = __attribute__((ext_vector_type(8))) short;  // 8 bf16 in 4 VGPRs
using f32x4  = __attribute__((ext_vector_type(4))) float;  // MFMA accumulator

#define NB 32
#define NP 1024
#define ND 256

__device__ __forceinline__ u16 f2bf(float x){
  u32 u = __float_as_uint(x);
  u += 0x7FFFu + ((u >> 16) & 1u);   // round-to-nearest-even
  return (u16)(u >> 16);
}

__device__ __forceinline__ float bf2f(u16 x){
  return __uint_as_float((u32)x << 16);
}

__device__ __forceinline__ void glds16(const void* g, void* l){
  __builtin_amdgcn_global_load_lds((const __attribute__((address_space(1))) void*)g,
                                   (__attribute__((address_space(3))) void*)l, 16, 0, 0);
}

// ---- fused prep: Pbf = bf16(P), PbfT = transpose, sbv[row] = P[row,:].wb -------
// One pass over P (64-row x 256-d tiles): replaces prep_rows + transpose_p
// (80 MB -> 64 MB HBM traffic, one fewer launch). sbv via in-wave shfl reduce
// (lanes tid&3 partition d into 4 x 64) - deterministic, no atomics.
__global__ void prep_pt(const float* __restrict__ P, const float* __restrict__ wi,
                        u16* __restrict__ Pbf, u16* __restrict__ PbfT,
                        float* __restrict__ sbv){
  const int b = blockIdx.y, jt = blockIdx.x;
  __shared__ __align__(16) u16 T[64][264];       // 33.8 KB (pad 264)
  const int tid = threadIdx.x;
  const int row = tid >> 2;                      // local j 0..63
  const int dq  = tid & 3;                       // d-quarter lane
  const size_t grow = (size_t)b * NP + jt * 64 + row;
  const float* prow = P + grow * ND;
  const float* wbp  = wi + ND;                   // wb = wi[256:512]
  float s = 0.f;
  #pragma unroll
  for (int it = 0; it < 4; ++it){
    const int d0 = it * 64 + dq * 16;            // per-lane 64B-contiguous chunks
    float4 a0 = *(const float4*)(prow + d0);
    float4 a1 = *(const float4*)(prow + d0 + 4);
    float4 a2 = *(const float4*)(prow + d0 + 8);
    float4 a3 = *(const float4*)(prow + d0 + 12);
    float4 w0 = *(const float4*)(wbp + d0);
    float4 w1 = *(const float4*)(wbp + d0 + 4);
    float4 w2 = *(const float4*)(wbp + d0 + 8);
    float4 w3 = *(const float4*)(wbp + d0 + 12);
    s += a0.x*w0.x + a0.y*w0.y + a0.z*w0.z + a0.w*w0.w;
    s += a1.x*w1.x + a1.y*w1.y + a1.z*w1.z + a1.w*w1.w;
    s += a2.x*w2.x + a2.y*w2.y + a2.z*w2.z + a2.w*w2.w;
    s += a3.x*w3.x + a3.y*w3.y + a3.z*w3.z + a3.w*w3.w;
    u16 tmp[16];
    tmp[0]=f2bf(a0.x); tmp[1]=f2bf(a0.y); tmp[2]=f2bf(a0.z); tmp[3]=f2bf(a0.w);
    tmp[4]=f2bf(a1.x); tmp[5]=f2bf(a1.y); tmp[6]=f2bf(a1.z); tmp[7]=f2bf(a1.w);
    tmp[8]=f2bf(a2.x); tmp[9]=f2bf(a2.y); tmp[10]=f2bf(a2.z); tmp[11]=f2bf(a2.w);
    tmp[12]=f2bf(a3.x); tmp[13]=f2bf(a3.y); tmp[14]=f2bf(a3.z); tmp[15]=f2bf(a3.w);
    *(uint4*)&T[row][d0]     = *(uint4*)tmp;
    *(uint4*)&T[row][d0 + 8] = *(uint4*)(tmp + 8);
    *(uint4*)(Pbf + grow * ND + d0)     = *(uint4*)tmp;
    *(uint4*)(Pbf + grow * ND + d0 + 8) = *(uint4*)(tmp + 8);
  }
  s += __shfl_xor(s, 1, 64);
  s += __shfl_xor(s, 2, 64);
  if (dq == 0) sbv[grow] = s;
  __syncthreads();
  #pragma unroll
  for (int it = 0; it < 8; ++it){
    int cc = tid + 256 * it;                     // 256 d-rows x 8 chunks
    int d = cc >> 3, c8 = cc & 7;
    u16 tmp[8];
    #pragma unroll
    for (int k = 0; k < 8; ++k) tmp[k] = T[c8 * 8 + k][d];
    *(uint4*)(PbfT + ((size_t)b * ND + d) * NP + jt * 64 + c8 * 8) = *(uint4*)tmp;
  }
}

// ------- prep_w: pack W fragment-major: Wp[((t*16+c)*64+lane)*8 + e] -------------
__global__ void prep_w(const float* __restrict__ w1, const float* __restrict__ w2,
                       const float* __restrict__ w3, u16* __restrict__ Wp){
  const int t = blockIdx.x;                       // 0..47
  const float* w = (t < 16) ? w1 : ((t < 32) ? w2 : w3);
  const int tid = threadIdx.x;
  #pragma unroll
  for (int j = 0; j < 4; ++j){
    int item = tid + 256 * j;                     // c*64 + lane
    int c = item >> 6, lane = item & 63;
    int ncol = ((t & 15) << 4) + (lane & 15);
    int k0 = 32 * c + 8 * (lane >> 4);
    u16 tmp[8];
    #pragma unroll
    for (int e = 0; e < 8; ++e) tmp[e] = f2bf(w[(size_t)(k0 + e) * 256 + ncol]);
    *(uint4*)(Wp + ((size_t)(t * 16 + c) * 64 + lane) * 8) = *(uint4*)tmp;
  }
}

// ---------------- attention: EXACT round-10 champion (81 us measured) ------------
// QBLK=64 (4 waves), KBLK=64, glds staging, split barriers, 2 blocks/CU.
// Bank rule (validated r4/r9/r10): b128 conflict-free iff quad=(addr/16)%8
// bijects (lo&7) at fixed hi. K: j*512+16*(ck^(j&7)); V: d*128+16*(kc^(d&7)).
// glds sources = whole-row 16B permutations (coalesced).
// NOTE: SQ_LDS_BANK_CONFLICT ~4.45M here is the glds DMA burst accounting
// (8.5 x 524288 DMA wave-ops, layout-invariant across r2/r3/r10/r14), NOT a
// fixable read conflict - frag reads are clean. Do not chase it.
__launch_bounds__(256, 2)
__global__ void attn_kernel(const float* __restrict__ P, const float* __restrict__ wi,
                            const u16* __restrict__ Pbf, const u16* __restrict__ PbfT,
                            const float* __restrict__ sbv, u16* __restrict__ attnb){
  const int p    = blockIdx.x;
  const int bid  = ((p & 7) << 6) | (p >> 3);     // 64 consecutive bids per XCD
  const int b    = bid >> 4;
  const int q0   = (bid & 15) << 6;
  const int tid  = threadIdx.x;
  const int wave = tid >> 6, lane = tid & 63, lo = lane & 15, hi = lane >> 4;

  __shared__ __align__(16) u16 KtA[64 * 256];     // 32 KB
  __shared__ __align__(16) u16 VtA[256 * 64];     // 32 KB
  __shared__ __align__(16) u16 Sp[4][16][72];     // 9.2 KB
  char* KtB = (char*)KtA;
  char* VtB = (char*)VtA;

  // ---- Q fragments (A-operand): q = P * wc, bf16, in regs ----
  bf16x8 qf[8];
  {
    const int qrow = q0 + wave * 16 + lo;
    const float* prow = P  + ((size_t)b * NP + qrow) * ND;
    const float* wcp  = wi + 512;
    #pragma unroll
    for (int c = 0; c < 8; ++c){
      const int d0 = 32 * c + 8 * hi;
      float4 a  = *(const float4*)(prow + d0);
      float4 a2 = *(const float4*)(prow + d0 + 4);
      float4 wa  = *(const float4*)(wcp + d0);
      float4 wa2 = *(const float4*)(wcp + d0 + 4);
      bf16x8 q;
      q[0]=(short)f2bf(a.x*wa.x);  q[1]=(short)f2bf(a.y*wa.y);
      q[2]=(short)f2bf(a.z*wa.z);  q[3]=(short)f2bf(a.w*wa.w);
      q[4]=(short)f2bf(a2.x*wa2.x); q[5]=(short)f2bf(a2.y*wa2.y);
      q[6]=(short)f2bf(a2.z*wa2.z); q[7]=(short)f2bf(a2.w*wa2.w);
      qf[c] = q;
    }
  }

  f32x4 of[16];
  #pragma unroll
  for (int t = 0; t < 16; ++t) of[t] = (f32x4){0.f,0.f,0.f,0.f};
  float mx[4] = {-1e30f,-1e30f,-1e30f,-1e30f};
  float ls[4] = {0.f,0.f,0.f,0.f};

  const u16* kslab = Pbf  + (size_t)b * NP * ND;   // row-major [j][d]
  const u16* vslab = PbfT + (size_t)b * ND * NP;   // d-major  [d][j]

  auto stageK = [&](int kt){
    const int kbase = kt * 64;
    #pragma unroll
    for (int it = 0; it < 8; ++it){
      int off = it * 4096 + tid * 16;             // linear LDS dest byte
      int j   = off >> 9;
      int ck  = ((off >> 4) & 31) ^ (j & 7);
      glds16((const char*)(kslab + (size_t)(kbase + j) * ND + ck * 8), KtB + off);
    }
  };
  auto stageV = [&](int kt){
    const int kbase = kt * 64;
    #pragma unroll
    for (int it = 0; it < 8; ++it){
      int off = it * 4096 + tid * 16;
      int d   = off >> 7;
      int kc  = ((off >> 4) & 7) ^ (d & 7);
      glds16((const char*)(vslab + (size_t)d * NP + kbase + kc * 8), VtB + off);
    }
  };

  float sbc[4], sbn[4];
  stageK(0);
  stageV(0);
  #pragma unroll
  for (int nt = 0; nt < 4; ++nt) sbc[nt] = sbv[(size_t)b * NP + nt * 16 + lo];
  __syncthreads();                                 // drain: K0,V0 valid

  for (int kt = 0; kt < 16; ++kt){
    // ---- S = Q K^T (reads Kt; V(kt) glds drained by this iter's entry sync) ----
    f32x4 s[4];
    #pragma unroll
    for (int nt = 0; nt < 4; ++nt){
      f32x4 acc = (f32x4){0.f,0.f,0.f,0.f};
      #pragma unroll
      for (int c = 0; c < 8; ++c){
        int j  = nt * 16 + lo;
        int ad = j * 512 + (((4 * c + hi) ^ (j & 7)) << 4);
        bf16x8 kf = *(const bf16x8*)(KtB + ad);
        acc = __builtin_amdgcn_mfma_f32_16x16x32_bf16(qf[c], kf, acc, 0, 0, 0);
      }
      s[nt] = acc;
      float sv = sbc[nt];
      #pragma unroll
      for (int r = 0; r < 4; ++r) s[nt][r] += sv;
    }

    __syncthreads();                  // barrier1: all waves done reading Kt
    if (kt < 15) stageK(kt + 1);      // in flight across softmax+PV; drains at b2

    // ---- deferred online softmax ----
    float md = -1e30f;
    #pragma unroll
    for (int nt = 0; nt < 4; ++nt)
      #pragma unroll
      for (int r = 0; r < 4; ++r) md = fmaxf(md, s[nt][r] - mx[r]);
    if (!__all(md <= 8.f)){
      // slow path: proper row maxima + rescale (tile 0, rare after)
      float scale[4];
      #pragma unroll
      for (int r = 0; r < 4; ++r){
        float v = fmaxf(fmaxf(s[0][r], s[1][r]), fmaxf(s[2][r], s[3][r]));
        v = fmaxf(v, __shfl_xor(v, 1, 64));
        v = fmaxf(v, __shfl_xor(v, 2, 64));
        v = fmaxf(v, __shfl_xor(v, 4, 64));
        v = fmaxf(v, __shfl_xor(v, 8, 64));
        float mnew = fmaxf(mx[r], v);
        scale[r] = __expf(mx[r] - mnew);
        mx[r] = mnew;
        ls[r] *= scale[r];
      }
      #pragma unroll
      for (int t = 0; t < 16; ++t)
        #pragma unroll
        for (int r = 0; r < 4; ++r) of[t][r] *= scale[r];
    }
    // common path: exp, per-lane partial sums, repack (p bounded by e^8)
    #pragma unroll
    for (int nt = 0; nt < 4; ++nt)
      #pragma unroll
      for (int r = 0; r < 4; ++r){
        float pv = __expf(s[nt][r] - mx[r]);
        ls[r] += pv;
        Sp[wave][4 * hi + r][16 * nt + lo] = f2bf(pv);
      }

    // ---- O += P V (reads Vt; Sp is within-wave, no barrier needed) ----
    #pragma unroll
    for (int kk = 0; kk < 2; ++kk){
      bf16x8 pa = *(const bf16x8*)&Sp[wave][lo][32 * kk + 8 * hi];
      #pragma unroll
      for (int t = 0; t < 16; ++t){
        int d  = 16 * t + lo;
        int ad = d * 128 + (((4 * kk + hi) ^ (d & 7)) << 4);
        bf16x8 vb = *(const bf16x8*)(VtB + ad);
        of[t] = __builtin_amdgcn_mfma_f32_16x16x32_bf16(pa, vb, of[t], 0, 0, 0);
      }
    }

    __syncthreads();                  // barrier2: Vt reads done; drains K(t+1) glds
    if (kt < 15){
      stageV(kt + 1);                 // in flight across next QK^T; drains at b1
      #pragma unroll
      for (int nt = 0; nt < 4; ++nt)
        sbn[nt] = sbv[(size_t)b * NP + (kt + 1) * 64 + nt * 16 + lo];
      sbc[0] = sbn[0]; sbc[1] = sbn[1]; sbc[2] = sbn[2]; sbc[3] = sbn[3];
    }
  }

  // ---- epilogue: one cross-lane ls reduce, O /= l, store bf16 ----
  #pragma unroll
  for (int r = 0; r < 4; ++r){
    ls[r] += __shfl_xor(ls[r], 1, 64);
    ls[r] += __shfl_xor(ls[r], 2, 64);
    ls[r] += __shfl_xor(ls[r], 4, 64);
    ls[r] += __shfl_xor(ls[r], 8, 64);
  }
  const int qrow = q0 + wave * 16;
  #pragma unroll
  for (int t = 0; t < 16; ++t){
    #pragma unroll
    for (int r = 0; r < 4; ++r){
      float o = of[t][r] / ls[r];
      attnb[((size_t)b * NP + qrow + 4 * hi + r) * ND + 16 * t + lo] = f2bf(o);
    }
  }
}

// ---------------- MLP: proper GEMM, M-tile 128, fused gate epilogue --------------
// NOTE: acc[3][8] = 96 VGPRs of accumulator. __launch_bounds__ min-waves MUST stay
// at 2 (VGPR budget 256): round-5's (256,4) capped the allocator at 64 VGPR and
// spilled all accumulators to scratch (WRITE_SIZE 33 -> 325 MB, 18 -> 136 us).
__launch_bounds__(256, 2)
__global__ void mlp_kernel(const u16* __restrict__ Pbf, const u16* __restrict__ attnb,
                           const u16* __restrict__ Wp,
                           const float* __restrict__ b1, const float* __restrict__ b2,
                           const float* __restrict__ b3, float* __restrict__ out){
  const int p    = blockIdx.x;
  const int swz  = ((p & 7) << 7) | (p >> 3);     // XCD-chunked
  const int mt   = swz >> 2, cg = swz & 3;
  const int tid  = threadIdx.x;
  const int wave = tid >> 6, lane = tid & 63, lo = lane & 15, hi = lane >> 4;
  const int tq   = 4 * cg + wave;
  const int m0   = mt * 128;

  __shared__ __align__(16) u16 Ab[2][128 * 64];   // 2 x 16 KB, swizzled

  f32x4 acc[3][8];
  #pragma unroll
  for (int e = 0; e < 3; ++e)
    #pragma unroll
    for (int m = 0; m < 8; ++m) acc[e][m] = (f32x4){0.f,0.f,0.f,0.f};

  auto stage = [&](int s, int buf){
    const u16* xs = (s < 4) ? (Pbf   + (size_t)m0 * ND + s * 64)
                            : (attnb + (size_t)m0 * ND + (s - 4) * 64);
    char* dst = (char*)Ab[buf];
    #pragma unroll
    for (int it = 0; it < 4; ++it){
      int off = it * 4096 + wave * 1024 + lane * 16;   // physical LDS byte
      int row = off >> 7;                               // 128B per row
      int cl  = (off & 127) ^ ((row & 7) << 4);         // logical byte in row
      glds16((const char*)(xs + (size_t)row * ND) + cl, dst + it * 4096 + wave * 1024);
    }
  };

  stage(0, 0);
  __syncthreads();

  for (int s = 0; s < 8; ++s){
    if (s < 7) stage(s + 1, (s + 1) & 1);
    const char* ab = (const char*)Ab[s & 1];
    #pragma unroll
    for (int cc = 0; cc < 2; ++cc){
      const int c = 2 * s + cc;
      bf16x8 wf[3];
      #pragma unroll
      for (int e = 0; e < 3; ++e)
        wf[e] = *(const bf16x8*)(Wp + ((size_t)((tq + 16 * e) * 16 + c) * 64 + lane) * 8);
      #pragma unroll
      for (int m = 0; m < 8; ++m){
        int row = 16 * m + lo;
        bf16x8 af = *(const bf16x8*)(ab + row * 128 + ((64 * cc + 16 * hi) ^ ((row & 7) << 4)));
        #pragma unroll
        for (int e = 0; e < 3; ++e)
          acc[e][m] = __builtin_amdgcn_mfma_f32_16x16x32_bf16(af, wf[e], acc[e][m], 0, 0, 0);
      }
    }
    __syncthreads();
  }

  // ---- fused gate epilogue ----
  const int d = 16 * tq + lo;
  const float bb1 = b1[d], bb2 = b2[d], bb3 = b3[d];
  #pragma unroll
  for (int m = 0; m < 8; ++m){
    #pragma unroll
    for (int r = 0; r < 4; ++r){
      const int row = m0 + 16 * m + 4 * hi + r;
      float y1 = acc[0][m][r] + bb1;
      float y2 = acc[1][m][r] + bb2;
      float y3 = acc[2][m][r] + bb3;
      float pv = bf2f(Pbf[(size_t)row * ND + d]);
      float e2 = __expf(2.f * y1);
      float z  = (e2 - 1.f) / (e2 + 1.f);          // tanh
      float rr = 1.f / (1.f + __expf(-y2));        // sigmoid
      float ff = 1.f / (1.f + __expf(-y3));        // sigmoid
      out[(size_t)row * ND + d] = rr * pv + ff * z;
    }
  }
}

extern "C" void kernel_launch(void* const* d_in, const int* in_sizes, int n_in,
                              void* d_out, int out_size, void* d_ws, size_t ws_size,
                              hipStream_t stream){
  const float* P  = (const float*)d_in[0];
  const float* wi = (const float*)d_in[1];
  const float* w1 = (const float*)d_in[2];
  const float* w2 = (const float*)d_in[3];
  const float* w3 = (const float*)d_in[4];
  const float* b1 = (const float*)d_in[5];
  const float* b2 = (const float*)d_in[6];
  const float* b3 = (const float*)d_in[7];
  float* out = (float*)d_out;

  char* ws = (char*)d_ws;
  u16*   Pbf   = (u16*)  (ws);                        // 16 MB
  u16*   PbfT  = (u16*)  (ws + (16u << 20));          // 16 MB
  u16*   attnb = (u16*)  (ws + (32u << 20));          // 16 MB
  u16*   Wp    = (u16*)  (ws + (48u << 20));          // 768 KB packed fragments
  float* sbv   = (float*)(ws + (49u << 20));          // 128 KB

  prep_pt<<<dim3(16, 32), 256, 0, stream>>>(P, wi, Pbf, PbfT, sbv);
  prep_w<<<48, 256, 0, stream>>>(w1, w2, w3, Wp);
  attn_kernel<<<512, 256, 0, stream>>>(P, wi, Pbf, PbfT, sbv, attnb);
  mlp_kernel<<<1024, 256, 0, stream>>>(Pbf, attnb, Wp, b1, b2, b3, out);
}

// Round 17
// 109.038 us; speedup vs baseline: 1.2970x; 1.0333x over previous
//
#include <hip/hip_runtime.h>
#include <hip/hip_bf16.h>

typedef unsigned short u16;
typedef unsigned int   u32;

using bf16x8 = __attribute__((ext_vector_type(8))) short;  // 8 bf16 in 4 VGPRs
using f32x4  = __attribute__((ext_vector_type(4))) float;  // MFMA accumulator

#define NB 32
#define NP 1024
#define ND 256

__device__ __forceinline__ u16 f2bf(float x){
  u32 u = __float_as_uint(x);
  u += 0x7FFFu + ((u >> 16) & 1u);   // round-to-nearest-even
  return (u16)(u >> 16);
}

__device__ __forceinline__ float bf2f(u16 x){
  return __uint_as_float((u32)x << 16);
}

__device__ __forceinline__ void glds16(const void* g, void* l){
  __builtin_amdgcn_global_load_lds((const __attribute__((address_space(1))) void*)g,
                                   (__attribute__((address_space(3))) void*)l, 16, 0, 0);
}

// ---- fused prep: Pbf = bf16(P), PbfT = transpose, sbv[row] = P[row,:].wb -------
__global__ void prep_pt(const float* __restrict__ P, const float* __restrict__ wi,
                        u16* __restrict__ Pbf, u16* __restrict__ PbfT,
                        float* __restrict__ sbv){
  const int b = blockIdx.y, jt = blockIdx.x;
  __shared__ __align__(16) u16 T[64][264];       // 33.8 KB (pad 264)
  const int tid = threadIdx.x;
  const int row = tid >> 2;                      // local j 0..63
  const int dq  = tid & 3;                       // d-quarter lane
  const size_t grow = (size_t)b * NP + jt * 64 + row;
  const float* prow = P + grow * ND;
  const float* wbp  = wi + ND;                   // wb = wi[256:512]
  float s = 0.f;
  #pragma unroll
  for (int it = 0; it < 4; ++it){
    const int d0 = it * 64 + dq * 16;            // per-lane 64B-contiguous chunks
    float4 a0 = *(const float4*)(prow + d0);
    float4 a1 = *(const float4*)(prow + d0 + 4);
    float4 a2 = *(const float4*)(prow + d0 + 8);
    float4 a3 = *(const float4*)(prow + d0 + 12);
    float4 w0 = *(const float4*)(wbp + d0);
    float4 w1 = *(const float4*)(wbp + d0 + 4);
    float4 w2 = *(const float4*)(wbp + d0 + 8);
    float4 w3 = *(const float4*)(wbp + d0 + 12);
    s += a0.x*w0.x + a0.y*w0.y + a0.z*w0.z + a0.w*w0.w;
    s += a1.x*w1.x + a1.y*w1.y + a1.z*w1.z + a1.w*w1.w;
    s += a2.x*w2.x + a2.y*w2.y + a2.z*w2.z + a2.w*w2.w;
    s += a3.x*w3.x + a3.y*w3.y + a3.z*w3.z + a3.w*w3.w;
    u16 tmp[16];
    tmp[0]=f2bf(a0.x); tmp[1]=f2bf(a0.y); tmp[2]=f2bf(a0.z); tmp[3]=f2bf(a0.w);
    tmp[4]=f2bf(a1.x); tmp[5]=f2bf(a1.y); tmp[6]=f2bf(a1.z); tmp[7]=f2bf(a1.w);
    tmp[8]=f2bf(a2.x); tmp[9]=f2bf(a2.y); tmp[10]=f2bf(a2.z); tmp[11]=f2bf(a2.w);
    tmp[12]=f2bf(a3.x); tmp[13]=f2bf(a3.y); tmp[14]=f2bf(a3.z); tmp[15]=f2bf(a3.w);
    *(uint4*)&T[row][d0]     = *(uint4*)tmp;
    *(uint4*)&T[row][d0 + 8] = *(uint4*)(tmp + 8);
    *(uint4*)(Pbf + grow * ND + d0)     = *(uint4*)tmp;
    *(uint4*)(Pbf + grow * ND + d0 + 8) = *(uint4*)(tmp + 8);
  }
  s += __shfl_xor(s, 1, 64);
  s += __shfl_xor(s, 2, 64);
  if (dq == 0) sbv[grow] = s;
  __syncthreads();
  #pragma unroll
  for (int it = 0; it < 8; ++it){
    int cc = tid + 256 * it;                     // 256 d-rows x 8 chunks
    int d = cc >> 3, c8 = cc & 7;
    u16 tmp[8];
    #pragma unroll
    for (int k = 0; k < 8; ++k) tmp[k] = T[c8 * 8 + k][d];
    *(uint4*)(PbfT + ((size_t)b * ND + d) * NP + jt * 64 + c8 * 8) = *(uint4*)tmp;
  }
}

// ------- prep_w: pack W fragment-major: Wp[((t*16+c)*64+lane)*8 + e] -------------
__global__ void prep_w(const float* __restrict__ w1, const float* __restrict__ w2,
                       const float* __restrict__ w3, u16* __restrict__ Wp){
  const int t = blockIdx.x;                       // 0..47
  const float* w = (t < 16) ? w1 : ((t < 32) ? w2 : w3);
  const int tid = threadIdx.x;
  #pragma unroll
  for (int j = 0; j < 4; ++j){
    int item = tid + 256 * j;                     // c*64 + lane
    int c = item >> 6, lane = item & 63;
    int ncol = ((t & 15) << 4) + (lane & 15);
    int k0 = 32 * c + 8 * (lane >> 4);
    u16 tmp[8];
    #pragma unroll
    for (int e = 0; e < 8; ++e) tmp[e] = f2bf(w[(size_t)(k0 + e) * 256 + ncol]);
    *(uint4*)(Wp + ((size_t)(t * 16 + c) * 64 + lane) * 8) = *(uint4*)tmp;
  }
}

// ---------------- attention: r16 champion + d-split PV ---------------------------
// r16 audit: all 4 waves read the SAME V fragments (each computes 16q x 256d) ->
// V LDS reads 4x redundant (128 of 264 b128/block-tile). d-split: each wave
// computes ALL 64 q x its own 64-d quarter -> V reads 128->32, Sp reads 8->32,
// net -72 b128/block-tile (~26% of LDS read time). Barrier count UNCHANGED (2):
// softmax moves before barrier1 (which now also publishes Sp/scales); stageV(t)
// overlaps QK^T+softmax, stageK(t+1) overlaps rescale+PV. Bank patterns all
// preserved: V read formula unchanged; Sp read quad (lo+4kk+hi)%8 bijective;
// sls/lfin reads are same-address broadcasts (free). of stays 16xf32x4/wave.
// K: j*512+16*(ck^(j&7)); V: d*128+16*(kc^(d&7)) (bank-validated r9/r10).
// SQ_LDS_BANK_CONFLICT ~4.45M = glds DMA burst accounting, not a read conflict.
__launch_bounds__(256, 2)
__global__ void attn_kernel(const float* __restrict__ P, const float* __restrict__ wi,
                            const u16* __restrict__ Pbf, const u16* __restrict__ PbfT,
                            const float* __restrict__ sbv, u16* __restrict__ attnb){
  const int p    = blockIdx.x;
  const int bid  = ((p & 7) << 6) | (p >> 3);     // 64 consecutive bids per XCD
  const int b    = bid >> 4;
  const int q0   = (bid & 15) << 6;
  const int tid  = threadIdx.x;
  const int wave = tid >> 6, lane = tid & 63, lo = lane & 15, hi = lane >> 4;

  __shared__ __align__(16) u16 KtA[64 * 256];     // 32 KB
  __shared__ __align__(16) u16 VtA[256 * 64];     // 32 KB
  __shared__ __align__(16) u16 Sp[4][16][72];     // 9.2 KB
  __shared__ float sls[4][16];                    // per-q rescale factors
  __shared__ float lfin[64];                      // final softmax sums
  __shared__ u32 fastf[4];                        // per-wave fast-path flags
  char* KtB = (char*)KtA;
  char* VtB = (char*)VtA;

  // ---- Q fragments (A-operand): q = P * wc, bf16, in regs ----
  bf16x8 qf[8];
  {
    const int qrow = q0 + wave * 16 + lo;
    const float* prow = P  + ((size_t)b * NP + qrow) * ND;
    const float* wcp  = wi + 512;
    #pragma unroll
    for (int c = 0; c < 8; ++c){
      const int d0 = 32 * c + 8 * hi;
      float4 a  = *(const float4*)(prow + d0);
      float4 a2 = *(const float4*)(prow + d0 + 4);
      float4 wa  = *(const float4*)(wcp + d0);
      float4 wa2 = *(const float4*)(wcp + d0 + 4);
      bf16x8 q;
      q[0]=(short)f2bf(a.x*wa.x);  q[1]=(short)f2bf(a.y*wa.y);
      q[2]=(short)f2bf(a.z*wa.z);  q[3]=(short)f2bf(a.w*wa.w);
      q[4]=(short)f2bf(a2.x*wa2.x); q[5]=(short)f2bf(a2.y*wa2.y);
      q[6]=(short)f2bf(a2.z*wa2.z); q[7]=(short)f2bf(a2.w*wa2.w);
      qf[c] = q;
    }
  }

  // of[qt][dt]: (16q x 16d) tile at q = q0+qt*16+4hi+r, d = wave*64+dt*16+lo
  f32x4 of[4][4];
  #pragma unroll
  for (int qt = 0; qt < 4; ++qt)
    #pragma unroll
    for (int dt = 0; dt < 4; ++dt) of[qt][dt] = (f32x4){0.f,0.f,0.f,0.f};
  float mx[4] = {-1e30f,-1e30f,-1e30f,-1e30f};
  float ls[4] = {0.f,0.f,0.f,0.f};

  const u16* kslab = Pbf  + (size_t)b * NP * ND;   // row-major [j][d]
  const u16* vslab = PbfT + (size_t)b * ND * NP;   // d-major  [d][j]

  auto stageK = [&](int kt){
    const int kbase = kt * 64;
    #pragma unroll
    for (int it = 0; it < 8; ++it){
      int off = it * 4096 + tid * 16;             // linear LDS dest byte
      int j   = off >> 9;
      int ck  = ((off >> 4) & 31) ^ (j & 7);
      glds16((const char*)(kslab + (size_t)(kbase + j) * ND + ck * 8), KtB + off);
    }
  };
  auto stageV = [&](int kt){
    const int kbase = kt * 64;
    #pragma unroll
    for (int it = 0; it < 8; ++it){
      int off = it * 4096 + tid * 16;
      int d   = off >> 7;
      int kc  = ((off >> 4) & 7) ^ (d & 7);
      glds16((const char*)(vslab + (size_t)d * NP + kbase + kc * 8), VtB + off);
    }
  };

  float sbc[4], sbn[4];
  stageK(0);
  stageV(0);
  #pragma unroll
  for (int nt = 0; nt < 4; ++nt) sbc[nt] = sbv[(size_t)b * NP + nt * 16 + lo];
  __syncthreads();                                 // drain: K0,V0 valid

  for (int kt = 0; kt < 16; ++kt){
    // ---- S = Q K^T (reads Kt; V(kt) glds drained by this iter's entry sync) ----
    f32x4 s[4];
    #pragma unroll
    for (int nt = 0; nt < 4; ++nt){
      f32x4 acc = (f32x4){0.f,0.f,0.f,0.f};
      #pragma unroll
      for (int c = 0; c < 8; ++c){
        int j  = nt * 16 + lo;
        int ad = j * 512 + (((4 * c + hi) ^ (j & 7)) << 4);
        bf16x8 kf = *(const bf16x8*)(KtB + ad);
        acc = __builtin_amdgcn_mfma_f32_16x16x32_bf16(qf[c], kf, acc, 0, 0, 0);
      }
      s[nt] = acc;
      float sv = sbc[nt];
      #pragma unroll
      for (int r = 0; r < 4; ++r) s[nt][r] += sv;
    }

    // ---- deferred online softmax (owning wave: its 16 q rows) ----
    float scale[4] = {1.f, 1.f, 1.f, 1.f};
    int fast = 1;
    {
      float md = -1e30f;
      #pragma unroll
      for (int nt = 0; nt < 4; ++nt)
        #pragma unroll
        for (int r = 0; r < 4; ++r) md = fmaxf(md, s[nt][r] - mx[r]);
      if (!__all(md <= 8.f)){
        fast = 0;
        #pragma unroll
        for (int r = 0; r < 4; ++r){
          float v = fmaxf(fmaxf(s[0][r], s[1][r]), fmaxf(s[2][r], s[3][r]));
          v = fmaxf(v, __shfl_xor(v, 1, 64));
          v = fmaxf(v, __shfl_xor(v, 2, 64));
          v = fmaxf(v, __shfl_xor(v, 4, 64));
          v = fmaxf(v, __shfl_xor(v, 8, 64));
          float mnew = fmaxf(mx[r], v);
          scale[r] = __expf(mx[r] - mnew);
          mx[r] = mnew;
          ls[r] *= scale[r];
        }
      }
    }
    // exp + per-lane partial sums + repack P to Sp (bounded by e^8)
    #pragma unroll
    for (int nt = 0; nt < 4; ++nt)
      #pragma unroll
      for (int r = 0; r < 4; ++r){
        float pv = __expf(s[nt][r] - mx[r]);
        ls[r] += pv;
        Sp[wave][4 * hi + r][16 * nt + lo] = f2bf(pv);
      }
    if (lane == 0) fastf[wave] = (u32)fast;
    if (lo == 0){
      #pragma unroll
      for (int r = 0; r < 4; ++r) sls[wave][4 * hi + r] = scale[r];
    }

    __syncthreads();                  // barrier1: Kt reads done; Sp/sls/flags visible
    if (kt < 15) stageK(kt + 1);      // in flight across rescale+PV; drains at b2

    // ---- cross-wave rescale of O (skipped when all 4 waves were fast) ----
    if (!(fastf[0] & fastf[1] & fastf[2] & fastf[3])){
      #pragma unroll
      for (int qt = 0; qt < 4; ++qt){
        #pragma unroll
        for (int r = 0; r < 4; ++r){
          float sc = sls[qt][4 * hi + r];          // same-addr per 16 lanes: broadcast
          #pragma unroll
          for (int dt = 0; dt < 4; ++dt) of[qt][dt][r] *= sc;
        }
      }
    }

    // ---- O += P V, d-split: this wave owns d in [wave*64, wave*64+64) ----
    #pragma unroll
    for (int kk = 0; kk < 2; ++kk){
      bf16x8 pa[4];
      #pragma unroll
      for (int qt = 0; qt < 4; ++qt)
        pa[qt] = *(const bf16x8*)&Sp[qt][lo][32 * kk + 8 * hi];
      #pragma unroll
      for (int dt = 0; dt < 4; ++dt){
        int d  = wave * 64 + dt * 16 + lo;
        int ad = d * 128 + (((4 * kk + hi) ^ (d & 7)) << 4);
        bf16x8 vb = *(const bf16x8*)(VtB + ad);
        #pragma unroll
        for (int qt = 0; qt < 4; ++qt)
          of[qt][dt] = __builtin_amdgcn_mfma_f32_16x16x32_bf16(pa[qt], vb, of[qt][dt], 0, 0, 0);
      }
    }

    __syncthreads();                  // barrier2: Vt+Sp reads done; drains K(t+1)
    if (kt < 15){
      stageV(kt + 1);                 // in flight across next QK^T+softmax; drains at b1
      #pragma unroll
      for (int nt = 0; nt < 4; ++nt)
        sbn[nt] = sbv[(size_t)b * NP + (kt + 1) * 64 + nt * 16 + lo];
      sbc[0] = sbn[0]; sbc[1] = sbn[1]; sbc[2] = sbn[2]; sbc[3] = sbn[3];
    }
  }

  // ---- epilogue: publish per-q l, then O /= l, store bf16 ----
  #pragma unroll
  for (int r = 0; r < 4; ++r){
    ls[r] += __shfl_xor(ls[r], 1, 64);
    ls[r] += __shfl_xor(ls[r], 2, 64);
    ls[r] += __shfl_xor(ls[r], 4, 64);
    ls[r] += __shfl_xor(ls[r], 8, 64);
  }
  if (lo == 0){
    #pragma unroll
    for (int r = 0; r < 4; ++r) lfin[wave * 16 + 4 * hi + r] = ls[r];
  }
  __syncthreads();
  #pragma unroll
  for (int qt = 0; qt < 4; ++qt){
    #pragma unroll
    for (int r = 0; r < 4; ++r){
      const float inv = 1.f / lfin[qt * 16 + 4 * hi + r];   // broadcast read
      const int qrow = q0 + qt * 16 + 4 * hi + r;
      #pragma unroll
      for (int dt = 0; dt < 4; ++dt){
        float o = of[qt][dt][r] * inv;
        attnb[((size_t)b * NP + qrow) * ND + wave * 64 + dt * 16 + lo] = f2bf(o);
      }
    }
  }
}

// ---------------- MLP: proper GEMM, M-tile 128, fused gate epilogue --------------
// NOTE: acc[3][8] = 96 VGPRs of accumulator. __launch_bounds__ min-waves MUST stay
// at 2 (VGPR budget 256): round-5's (256,4) capped the allocator at 64 VGPR and
// spilled all accumulators to scratch (WRITE_SIZE 33 -> 325 MB, 18 -> 136 us).
__launch_bounds__(256, 2)
__global__ void mlp_kernel(const u16* __restrict__ Pbf, const u16* __restrict__ attnb,
                           const u16* __restrict__ Wp,
                           const float* __restrict__ b1, const float* __restrict__ b2,
                           const float* __restrict__ b3, float* __restrict__ out){
  const int p    = blockIdx.x;
  const int swz  = ((p & 7) << 7) | (p >> 3);     // XCD-chunked
  const int mt   = swz >> 2, cg = swz & 3;
  const int tid  = threadIdx.x;
  const int wave = tid >> 6, lane = tid & 63, lo = lane & 15, hi = lane >> 4;
  const int tq   = 4 * cg + wave;
  const int m0   = mt * 128;

  __shared__ __align__(16) u16 Ab[2][128 * 64];   // 2 x 16 KB, swizzled

  f32x4 acc[3][8];
  #pragma unroll
  for (int e = 0; e < 3; ++e)
    #pragma unroll
    for (int m = 0; m < 8; ++m) acc[e][m] = (f32x4){0.f,0.f,0.f,0.f};

  auto stage = [&](int s, int buf){
    const u16* xs = (s < 4) ? (Pbf   + (size_t)m0 * ND + s * 64)
                            : (attnb + (size_t)m0 * ND + (s - 4) * 64);
    char* dst = (char*)Ab[buf];
    #pragma unroll
    for (int it = 0; it < 4; ++it){
      int off = it * 4096 + wave * 1024 + lane * 16;   // physical LDS byte
      int row = off >> 7;                               // 128B per row
      int cl  = (off & 127) ^ ((row & 7) << 4);         // logical byte in row
      glds16((const char*)(xs + (size_t)row * ND) + cl, dst + it * 4096 + wave * 1024);
    }
  };

  stage(0, 0);
  __syncthreads();

  for (int s = 0; s < 8; ++s){
    if (s < 7) stage(s + 1, (s + 1) & 1);
    const char* ab = (const char*)Ab[s & 1];
    #pragma unroll
    for (int cc = 0; cc < 2; ++cc){
      const int c = 2 * s + cc;
      bf16x8 wf[3];
      #pragma unroll
      for (int e = 0; e < 3; ++e)
        wf[e] = *(const bf16x8*)(Wp + ((size_t)((tq + 16 * e) * 16 + c) * 64 + lane) * 8);
      #pragma unroll
      for (int m = 0; m < 8; ++m){
        int row = 16 * m + lo;
        bf16x8 af = *(const bf16x8*)(ab + row * 128 + ((64 * cc + 16 * hi) ^ ((row & 7) << 4)));
        #pragma unroll
        for (int e = 0; e < 3; ++e)
          acc[e][m] = __builtin_amdgcn_mfma_f32_16x16x32_bf16(af, wf[e], acc[e][m], 0, 0, 0);
      }
    }
    __syncthreads();
  }

  // ---- fused gate epilogue ----
  const int d = 16 * tq + lo;
  const float bb1 = b1[d], bb2 = b2[d], bb3 = b3[d];
  #pragma unroll
  for (int m = 0; m < 8; ++m){
    #pragma unroll
    for (int r = 0; r < 4; ++r){
      const int row = m0 + 16 * m + 4 * hi + r;
      float y1 = acc[0][m][r] + bb1;
      float y2 = acc[1][m][r] + bb2;
      float y3 = acc[2][m][r] + bb3;
      float pv = bf2f(Pbf[(size_t)row * ND + d]);
      float e2 = __expf(2.f * y1);
      float z  = (e2 - 1.f) / (e2 + 1.f);          // tanh
      float rr = 1.f / (1.f + __expf(-y2));        // sigmoid
      float ff = 1.f / (1.f + __expf(-y3));        // sigmoid
      out[(size_t)row * ND + d] = rr * pv + ff * z;
    }
  }
}

extern "C" void kernel_launch(void* const* d_in, const int* in_sizes, int n_in,
                              void* d_out, int out_size, void* d_ws, size_t ws_size,
                              hipStream_t stream){
  const float* P  = (const float*)d_in[0];
  const float* wi = (const float*)d_in[1];
  const float* w1 = (const float*)d_in[2];
  const float* w2 = (const float*)d_in[3];
  const float* w3 = (const float*)d_in[4];
  const float* b1 = (const float*)d_in[5];
  const float* b2 = (const float*)d_in[6];
  const float* b3 = (const float*)d_in[7];
  float* out = (float*)d_out;

  char* ws = (char*)d_ws;
  u16*   Pbf   = (u16*)  (ws);                        // 16 MB
  u16*   PbfT  = (u16*)  (ws + (16u << 20));          // 16 MB
  u16*   attnb = (u16*)  (ws + (32u << 20));          // 16 MB
  u16*   Wp    = (u16*)  (ws + (48u << 20));          // 768 KB packed fragments
  float* sbv   = (float*)(ws + (49u << 20));          // 128 KB

  prep_pt<<<dim3(16, 32), 256, 0, stream>>>(P, wi, Pbf, PbfT, sbv);
  prep_w<<<48, 256, 0, stream>>>(w1, w2, w3, Wp);
  attn_kernel<<<512, 256, 0, stream>>>(P, wi, Pbf, PbfT, sbv, attnb);
  mlp_kernel<<<1024, 256, 0, stream>>>(Pbf, attnb, Wp, b1, b2, b3, out);
}

// Round 19
// 108.035 us; speedup vs baseline: 1.3091x; 1.0093x over previous
//
#include <hip/hip_runtime.h>
#include <hip/hip_bf16.h>

typedef unsigned short u16;
typedef unsigned int   u32;
typedef unsigned char  u8;

using bf16x8 = __attribute__((ext_vector_type(8))) short;  // 8 bf16 in 4 VGPRs
using f32x4  = __attribute__((ext_vector_type(4))) float;  // MFMA accumulator

#define NB 32
#define NP 1024
#define ND 256

__device__ __forceinline__ u16 f2bf(float x){
  u32 u = __float_as_uint(x);
  u += 0x7FFFu + ((u >> 16) & 1u);   // round-to-nearest-even
  return (u16)(u >> 16);
}

__device__ __forceinline__ float bf2f(u16 x){
  return __uint_as_float((u32)x << 16);
}

// ---- fp8 e4m3fn pack: 2 floats -> 2 bytes (low/high half of u32) ----
// NOTE: the builtin's word-select arg must be a LITERAL -> template dispatch
// (same constraint class as global_load_lds's size arg).
#if __has_builtin(__builtin_amdgcn_cvt_pk_fp8_f32)
template<bool HI>
__device__ __forceinline__ u32 pk_fp8(float a, float b, u32 old){
  return (u32)__builtin_amdgcn_cvt_pk_fp8_f32(a, b, (int)old, HI);
}
#else
__device__ __forceinline__ u8 f2e4m3(float x){
  u32 b = __float_as_uint(x);
  u32 s = (b >> 31) << 7;
  float ax = __uint_as_float(b & 0x7fffffffu);
  if (!(ax < 464.f)) return (u8)(s | 0x7E);            // sat (fn: no inf), NaN->max
  if (ax < 0.001953125f) return (u8)s;                 // < 2^-9 -> 0
  if (ax < 0.015625f){                                 // denormal: q = round(x*512)
    u32 m = (u32)__float2int_rn(ax * 512.f);
    return (u8)(s | m);
  }
  u32 bb = b & 0x7fffffffu;
  bb += 0x7ffffu + ((bb >> 20) & 1u);                  // RNE to 3-bit mantissa
  int e = (int)(bb >> 23) - 127 + 7;
  u32 m = (bb >> 20) & 7u;
  if (e > 15 || (e == 15 && m == 7)) return (u8)(s | 0x7E);
  return (u8)(s | ((u32)e << 3) | m);
}
template<bool HI>
__device__ __forceinline__ u32 pk_fp8(float a, float b, u32 old){
  u32 v = (u32)f2e4m3(a) | ((u32)f2e4m3(b) << 8);
  return HI ? ((old & 0xFFFFu) | (v << 16)) : ((old & 0xFFFF0000u) | v);
}
#endif

__device__ __forceinline__ void glds16(const void* g, void* l){
  __builtin_amdgcn_global_load_lds((const __attribute__((address_space(1))) void*)g,
                                   (__attribute__((address_space(3))) void*)l, 16, 0, 0);
}

// ---- fused prep: Pbf = bf16(P), PbfT = transpose, P8 = e4m3(P), sbv = P.wb -----
__global__ void prep_pt(const float* __restrict__ P, const float* __restrict__ wi,
                        u16* __restrict__ Pbf, u16* __restrict__ PbfT,
                        u8* __restrict__ P8, float* __restrict__ sbv){
  const int b = blockIdx.y, jt = blockIdx.x;
  __shared__ __align__(16) u16 T[64][264];       // 33.8 KB (pad 264)
  const int tid = threadIdx.x;
  const int row = tid >> 2;                      // local j 0..63
  const int dq  = tid & 3;                       // d-quarter lane
  const size_t grow = (size_t)b * NP + jt * 64 + row;
  const float* prow = P + grow * ND;
  const float* wbp  = wi + ND;                   // wb = wi[256:512]
  float s = 0.f;
  #pragma unroll
  for (int it = 0; it < 4; ++it){
    const int d0 = it * 64 + dq * 16;            // per-lane 64B-contiguous chunks
    float4 a0 = *(const float4*)(prow + d0);
    float4 a1 = *(const float4*)(prow + d0 + 4);
    float4 a2 = *(const float4*)(prow + d0 + 8);
    float4 a3 = *(const float4*)(prow + d0 + 12);
    float4 w0 = *(const float4*)(wbp + d0);
    float4 w1 = *(const float4*)(wbp + d0 + 4);
    float4 w2 = *(const float4*)(wbp + d0 + 8);
    float4 w3 = *(const float4*)(wbp + d0 + 12);
    s += a0.x*w0.x + a0.y*w0.y + a0.z*w0.z + a0.w*w0.w;
    s += a1.x*w1.x + a1.y*w1.y + a1.z*w1.z + a1.w*w1.w;
    s += a2.x*w2.x + a2.y*w2.y + a2.z*w2.z + a2.w*w2.w;
    s += a3.x*w3.x + a3.y*w3.y + a3.z*w3.z + a3.w*w3.w;
    u16 tmp[16];
    tmp[0]=f2bf(a0.x); tmp[1]=f2bf(a0.y); tmp[2]=f2bf(a0.z); tmp[3]=f2bf(a0.w);
    tmp[4]=f2bf(a1.x); tmp[5]=f2bf(a1.y); tmp[6]=f2bf(a1.z); tmp[7]=f2bf(a1.w);
    tmp[8]=f2bf(a2.x); tmp[9]=f2bf(a2.y); tmp[10]=f2bf(a2.z); tmp[11]=f2bf(a2.w);
    tmp[12]=f2bf(a3.x); tmp[13]=f2bf(a3.y); tmp[14]=f2bf(a3.z); tmp[15]=f2bf(a3.w);
    *(uint4*)&T[row][d0]     = *(uint4*)tmp;
    *(uint4*)&T[row][d0 + 8] = *(uint4*)(tmp + 8);
    *(uint4*)(Pbf + grow * ND + d0)     = *(uint4*)tmp;
    *(uint4*)(Pbf + grow * ND + d0 + 8) = *(uint4*)(tmp + 8);
    // fp8 copy of K (16 values -> 16 bytes)
    u32 q0 = pk_fp8<false>(a0.x, a0.y, 0); q0 = pk_fp8<true>(a0.z, a0.w, q0);
    u32 q1 = pk_fp8<false>(a1.x, a1.y, 0); q1 = pk_fp8<true>(a1.z, a1.w, q1);
    u32 q2 = pk_fp8<false>(a2.x, a2.y, 0); q2 = pk_fp8<true>(a2.z, a2.w, q2);
    u32 q3 = pk_fp8<false>(a3.x, a3.y, 0); q3 = pk_fp8<true>(a3.z, a3.w, q3);
    uint4 pq; pq.x = q0; pq.y = q1; pq.z = q2; pq.w = q3;
    *(uint4*)(P8 + grow * ND + d0) = pq;
  }
  s += __shfl_xor(s, 1, 64);
  s += __shfl_xor(s, 2, 64);
  if (dq == 0) sbv[grow] = s;
  __syncthreads();
  #pragma unroll
  for (int it = 0; it < 8; ++it){
    int cc = tid + 256 * it;                     // 256 d-rows x 8 chunks
    int d = cc >> 3, c8 = cc & 7;
    u16 tmp[8];
    #pragma unroll
    for (int k = 0; k < 8; ++k) tmp[k] = T[c8 * 8 + k][d];
    *(uint4*)(PbfT + ((size_t)b * ND + d) * NP + jt * 64 + c8 * 8) = *(uint4*)tmp;
  }
}

// ------- prep_w: pack W fragment-major: Wp[((t*16+c)*64+lane)*8 + e] -------------
__global__ void prep_w(const float* __restrict__ w1, const float* __restrict__ w2,
                       const float* __restrict__ w3, u16* __restrict__ Wp){
  const int t = blockIdx.x;                       // 0..47
  const float* w = (t < 16) ? w1 : ((t < 32) ? w2 : w3);
  const int tid = threadIdx.x;
  #pragma unroll
  for (int j = 0; j < 4; ++j){
    int item = tid + 256 * j;                     // c*64 + lane
    int c = item >> 6, lane = item & 63;
    int ncol = ((t & 15) << 4) + (lane & 15);
    int k0 = 32 * c + 8 * (lane >> 4);
    u16 tmp[8];
    #pragma unroll
    for (int e = 0; e < 8; ++e) tmp[e] = f2bf(w[(size_t)(k0 + e) * 256 + ncol]);
    *(uint4*)(Wp + ((size_t)(t * 16 + c) * 64 + lane) * 8) = *(uint4*)tmp;
  }
}

// ---------------- attention: r17 champion + fp8 QK^T -----------------------------
// r17 established: LDS read bytes are 1:1 on the critical path (d-split removed
// 72KB/block-tile -> exactly -7.5us). Remaining ledger: K 128KB (67%), V 32, Sp 32.
// fp8 e4m3 QK^T (mfma_f32_16x16x32_fp8_fp8 = same shape & rate as bf16, m11):
// K reads become b64 -> -64KB/block-tile; staging -16KB/tile. Q pre-scaled x16
// (q~0.03 is e4m3-denormal; 16q~0.5 is normal range) and folded back as x1/16
// into the sb-add. V/P/Sp stay bf16 (V error enters O linearly).
// K8 layout (256B fp8 rows, bijection rule): store 16B-unit t' = t ^ (j&7);
// read 8B chunk ck=4c+hi at 16*((2c+(hi>>1))^(j&7)) + 8*(hi&1) -> 2-way (free).
// V: d*128+16*(kc^(d&7)); Sp as r17. SQ_LDS_BANK_CONFLICT ~5M = DMA accounting.
__launch_bounds__(256, 2)
__global__ void attn_kernel(const float* __restrict__ P, const float* __restrict__ wi,
                            const u8* __restrict__ P8, const u16* __restrict__ PbfT,
                            const float* __restrict__ sbv, u16* __restrict__ attnb){
  const int p    = blockIdx.x;
  const int bid  = ((p & 7) << 6) | (p >> 3);     // 64 consecutive bids per XCD
  const int b    = bid >> 4;
  const int q0   = (bid & 15) << 6;
  const int tid  = threadIdx.x;
  const int wave = tid >> 6, lane = tid & 63, lo = lane & 15, hi = lane >> 4;

  __shared__ __align__(16) u8  Kt8[64 * 256];     // 16 KB (fp8)
  __shared__ __align__(16) u16 VtA[256 * 64];     // 32 KB
  __shared__ __align__(16) u16 Sp[4][16][72];     // 9.2 KB
  __shared__ float sls[4][16];                    // per-q rescale factors
  __shared__ float lfin[64];                      // final softmax sums
  __shared__ u32 fastf[4];                        // per-wave fast-path flags
  char* KtB = (char*)Kt8;
  char* VtB = (char*)VtA;

  // ---- Q fragments (A-operand, fp8): q = 16 * P * wc ----
  long qf8[8];
  {
    const int qrow = q0 + wave * 16 + lo;
    const float* prow = P  + ((size_t)b * NP + qrow) * ND;
    const float* wcp  = wi + 512;
    #pragma unroll
    for (int c = 0; c < 8; ++c){
      const int d0 = 32 * c + 8 * hi;
      float4 a  = *(const float4*)(prow + d0);
      float4 a2 = *(const float4*)(prow + d0 + 4);
      float4 wa  = *(const float4*)(wcp + d0);
      float4 wa2 = *(const float4*)(wcp + d0 + 4);
      u32 w0 = pk_fp8<false>(16.f*a.x*wa.x,  16.f*a.y*wa.y,  0);
      w0     = pk_fp8<true >(16.f*a.z*wa.z,  16.f*a.w*wa.w,  w0);
      u32 w1 = pk_fp8<false>(16.f*a2.x*wa2.x, 16.f*a2.y*wa2.y, 0);
      w1     = pk_fp8<true >(16.f*a2.z*wa2.z, 16.f*a2.w*wa2.w, w1);
      qf8[c] = (long)(((unsigned long long)w1 << 32) | w0);
    }
  }

  // of[qt][dt]: (16q x 16d) tile at q = q0+qt*16+4hi+r, d = wave*64+dt*16+lo
  f32x4 of[4][4];
  #pragma unroll
  for (int qt = 0; qt < 4; ++qt)
    #pragma unroll
    for (int dt = 0; dt < 4; ++dt) of[qt][dt] = (f32x4){0.f,0.f,0.f,0.f};
  float mx[4] = {-1e30f,-1e30f,-1e30f,-1e30f};
  float ls[4] = {0.f,0.f,0.f,0.f};

  const u8*  kslab = P8   + (size_t)b * NP * ND;   // fp8 row-major [j][d]
  const u16* vslab = PbfT + (size_t)b * ND * NP;   // bf16 d-major [d][j]

  auto stageK = [&](int kt){
    const int kbase = kt * 64;
    #pragma unroll
    for (int it = 0; it < 4; ++it){
      int off = it * 4096 + tid * 16;             // linear LDS dest byte
      int j   = off >> 8;                          // 256B fp8 rows
      int u   = ((off >> 4) & 15) ^ (j & 7);       // source 16B unit
      glds16((const char*)(kslab + (size_t)(kbase + j) * ND + u * 16), KtB + off);
    }
  };
  auto stageV = [&](int kt){
    const int kbase = kt * 64;
    #pragma unroll
    for (int it = 0; it < 8; ++it){
      int off = it * 4096 + tid * 16;
      int d   = off >> 7;
      int kc  = ((off >> 4) & 7) ^ (d & 7);
      glds16((const char*)(vslab + (size_t)d * NP + kbase + kc * 8), VtB + off);
    }
  };

  float sbc[4], sbn[4];
  stageK(0);
  stageV(0);
  #pragma unroll
  for (int nt = 0; nt < 4; ++nt) sbc[nt] = sbv[(size_t)b * NP + nt * 16 + lo];
  __syncthreads();                                 // drain: K0,V0 valid

  for (int kt = 0; kt < 16; ++kt){
    // ---- S = (16Q) K^T / 16 (fp8 MFMA; reads Kt8) ----
    f32x4 s[4];
    #pragma unroll
    for (int nt = 0; nt < 4; ++nt){
      f32x4 acc = (f32x4){0.f,0.f,0.f,0.f};
      #pragma unroll
      for (int c = 0; c < 8; ++c){
        int j  = nt * 16 + lo;
        int ad = j * 256 + (((2 * c + (hi >> 1)) ^ (j & 7)) << 4) + 8 * (hi & 1);
        long kf8 = *(const long*)(KtB + ad);
        acc = __builtin_amdgcn_mfma_f32_16x16x32_fp8_fp8(qf8[c], kf8, acc, 0, 0, 0);
      }
      float sv = sbc[nt];
      #pragma unroll
      for (int r = 0; r < 4; ++r) s[nt][r] = fmaf(acc[r], 0.0625f, sv);
    }

    // ---- deferred online softmax (owning wave: its 16 q rows) ----
    float scale[4] = {1.f, 1.f, 1.f, 1.f};
    int fast = 1;
    {
      float md = -1e30f;
      #pragma unroll
      for (int nt = 0; nt < 4; ++nt)
        #pragma unroll
        for (int r = 0; r < 4; ++r) md = fmaxf(md, s[nt][r] - mx[r]);
      if (!__all(md <= 8.f)){
        fast = 0;
        #pragma unroll
        for (int r = 0; r < 4; ++r){
          float v = fmaxf(fmaxf(s[0][r], s[1][r]), fmaxf(s[2][r], s[3][r]));
          v = fmaxf(v, __shfl_xor(v, 1, 64));
          v = fmaxf(v, __shfl_xor(v, 2, 64));
          v = fmaxf(v, __shfl_xor(v, 4, 64));
          v = fmaxf(v, __shfl_xor(v, 8, 64));
          float mnew = fmaxf(mx[r], v);
          scale[r] = __expf(mx[r] - mnew);
          mx[r] = mnew;
          ls[r] *= scale[r];
        }
      }
    }
    // exp + per-lane partial sums + repack P to Sp (bounded by e^8)
    #pragma unroll
    for (int nt = 0; nt < 4; ++nt)
      #pragma unroll
      for (int r = 0; r < 4; ++r){
        float pv = __expf(s[nt][r] - mx[r]);
        ls[r] += pv;
        Sp[wave][4 * hi + r][16 * nt + lo] = f2bf(pv);
      }
    if (lane == 0) fastf[wave] = (u32)fast;
    if (lo == 0){
      #pragma unroll
      for (int r = 0; r < 4; ++r) sls[wave][4 * hi + r] = scale[r];
    }

    __syncthreads();                  // barrier1: Kt reads done; Sp/sls/flags visible
    if (kt < 15) stageK(kt + 1);      // in flight across rescale+PV; drains at b2

    // ---- cross-wave rescale of O (skipped when all 4 waves were fast) ----
    if (!(fastf[0] & fastf[1] & fastf[2] & fastf[3])){
      #pragma unroll
      for (int qt = 0; qt < 4; ++qt){
        #pragma unroll
        for (int r = 0; r < 4; ++r){
          float sc = sls[qt][4 * hi + r];          // same-addr per 16 lanes: broadcast
          #pragma unroll
          for (int dt = 0; dt < 4; ++dt) of[qt][dt][r] *= sc;
        }
      }
    }

    // ---- O += P V, d-split: this wave owns d in [wave*64, wave*64+64) ----
    #pragma unroll
    for (int kk = 0; kk < 2; ++kk){
      bf16x8 pa[4];
      #pragma unroll
      for (int qt = 0; qt < 4; ++qt)
        pa[qt] = *(const bf16x8*)&Sp[qt][lo][32 * kk + 8 * hi];
      #pragma unroll
      for (int dt = 0; dt < 4; ++dt){
        int d  = wave * 64 + dt * 16 + lo;
        int ad = d * 128 + (((4 * kk + hi) ^ (d & 7)) << 4);
        bf16x8 vb = *(const bf16x8*)(VtB + ad);
        #pragma unroll
        for (int qt = 0; qt < 4; ++qt)
          of[qt][dt] = __builtin_amdgcn_mfma_f32_16x16x32_bf16(pa[qt], vb, of[qt][dt], 0, 0, 0);
      }
    }

    __syncthreads();                  // barrier2: Vt+Sp reads done; drains K(t+1)
    if (kt < 15){
      stageV(kt + 1);                 // in flight across next QK^T+softmax; drains at b1
      #pragma unroll
      for (int nt = 0; nt < 4; ++nt)
        sbn[nt] = sbv[(size_t)b * NP + (kt + 1) * 64 + nt * 16 + lo];
      sbc[0] = sbn[0]; sbc[1] = sbn[1]; sbc[2] = sbn[2]; sbc[3] = sbn[3];
    }
  }

  // ---- epilogue: publish per-q l, then O /= l, store bf16 ----
  #pragma unroll
  for (int r = 0; r < 4; ++r){
    ls[r] += __shfl_xor(ls[r], 1, 64);
    ls[r] += __shfl_xor(ls[r], 2, 64);
    ls[r] += __shfl_xor(ls[r], 4, 64);
    ls[r] += __shfl_xor(ls[r], 8, 64);
  }
  if (lo == 0){
    #pragma unroll
    for (int r = 0; r < 4; ++r) lfin[wave * 16 + 4 * hi + r] = ls[r];
  }
  __syncthreads();
  #pragma unroll
  for (int qt = 0; qt < 4; ++qt){
    #pragma unroll
    for (int r = 0; r < 4; ++r){
      const float inv = 1.f / lfin[qt * 16 + 4 * hi + r];   // broadcast read
      const int qrow = q0 + qt * 16 + 4 * hi + r;
      #pragma unroll
      for (int dt = 0; dt < 4; ++dt){
        float o = of[qt][dt][r] * inv;
        attnb[((size_t)b * NP + qrow) * ND + wave * 64 + dt * 16 + lo] = f2bf(o);
      }
    }
  }
}

// ---------------- MLP: proper GEMM, M-tile 128, fused gate epilogue --------------
// NOTE: acc[3][8] = 96 VGPRs of accumulator. __launch_bounds__ min-waves MUST stay
// at 2 (VGPR budget 256): round-5's (256,4) capped the allocator at 64 VGPR and
// spilled all accumulators to scratch (WRITE_SIZE 33 -> 325 MB, 18 -> 136 us).
__launch_bounds__(256, 2)
__global__ void mlp_kernel(const u16* __restrict__ Pbf, const u16* __restrict__ attnb,
                           const u16* __restrict__ Wp,
                           const float* __restrict__ b1, const float* __restrict__ b2,
                           const float* __restrict__ b3, float* __restrict__ out){
  const int p    = blockIdx.x;
  const int swz  = ((p & 7) << 7) | (p >> 3);     // XCD-chunked
  const int mt   = swz >> 2, cg = swz & 3;
  const int tid  = threadIdx.x;
  const int wave = tid >> 6, lane = tid & 63, lo = lane & 15, hi = lane >> 4;
  const int tq   = 4 * cg + wave;
  const int m0   = mt * 128;

  __shared__ __align__(16) u16 Ab[2][128 * 64];   // 2 x 16 KB, swizzled

  f32x4 acc[3][8];
  #pragma unroll
  for (int e = 0; e < 3; ++e)
    #pragma unroll
    for (int m = 0; m < 8; ++m) acc[e][m] = (f32x4){0.f,0.f,0.f,0.f};

  auto stage = [&](int s, int buf){
    const u16* xs = (s < 4) ? (Pbf   + (size_t)m0 * ND + s * 64)
                            : (attnb + (size_t)m0 * ND + (s - 4) * 64);
    char* dst = (char*)Ab[buf];
    #pragma unroll
    for (int it = 0; it < 4; ++it){
      int off = it * 4096 + wave * 1024 + lane * 16;   // physical LDS byte
      int row = off >> 7;                               // 128B per row
      int cl  = (off & 127) ^ ((row & 7) << 4);         // logical byte in row
      glds16((const char*)(xs + (size_t)row * ND) + cl, dst + it * 4096 + wave * 1024);
    }
  };

  stage(0, 0);
  __syncthreads();

  for (int s = 0; s < 8; ++s){
    if (s < 7) stage(s + 1, (s + 1) & 1);
    const char* ab = (const char*)Ab[s & 1];
    #pragma unroll
    for (int cc = 0; cc < 2; ++cc){
      const int c = 2 * s + cc;
      bf16x8 wf[3];
      #pragma unroll
      for (int e = 0; e < 3; ++e)
        wf[e] = *(const bf16x8*)(Wp + ((size_t)((tq + 16 * e) * 16 + c) * 64 + lane) * 8);
      #pragma unroll
      for (int m = 0; m < 8; ++m){
        int row = 16 * m + lo;
        bf16x8 af = *(const bf16x8*)(ab + row * 128 + ((64 * cc + 16 * hi) ^ ((row & 7) << 4)));
        #pragma unroll
        for (int e = 0; e < 3; ++e)
          acc[e][m] = __builtin_amdgcn_mfma_f32_16x16x32_bf16(af, wf[e], acc[e][m], 0, 0, 0);
      }
    }
    __syncthreads();
  }

  // ---- fused gate epilogue ----
  const int d = 16 * tq + lo;
  const float bb1 = b1[d], bb2 = b2[d], bb3 = b3[d];
  #pragma unroll
  for (int m = 0; m < 8; ++m){
    #pragma unroll
    for (int r = 0; r < 4; ++r){
      const int row = m0 + 16 * m + 4 * hi + r;
      float y1 = acc[0][m][r] + bb1;
      float y2 = acc[1][m][r] + bb2;
      float y3 = acc[2][m][r] + bb3;
      float pv = bf2f(Pbf[(size_t)row * ND + d]);
      float e2 = __expf(2.f * y1);
      float z  = (e2 - 1.f) / (e2 + 1.f);          // tanh
      float rr = 1.f / (1.f + __expf(-y2));        // sigmoid
      float ff = 1.f / (1.f + __expf(-y3));        // sigmoid
      out[(size_t)row * ND + d] = rr * pv + ff * z;
    }
  }
}

extern "C" void kernel_launch(void* const* d_in, const int* in_sizes, int n_in,
                              void* d_out, int out_size, void* d_ws, size_t ws_size,
                              hipStream_t stream){
  const float* P  = (const float*)d_in[0];
  const float* wi = (const float*)d_in[1];
  const float* w1 = (const float*)d_in[2];
  const float* w2 = (const float*)d_in[3];
  const float* w3 = (const float*)d_in[4];
  const float* b1 = (const float*)d_in[5];
  const float* b2 = (const float*)d_in[6];
  const float* b3 = (const float*)d_in[7];
  float* out = (float*)d_out;

  char* ws = (char*)d_ws;
  u16*   Pbf   = (u16*)  (ws);                        // 16 MB
  u16*   PbfT  = (u16*)  (ws + (16u << 20));          // 16 MB
  u16*   attnb = (u16*)  (ws + (32u << 20));          // 16 MB
  u16*   Wp    = (u16*)  (ws + (48u << 20));          // 768 KB packed fragments
  float* sbv   = (float*)(ws + (49u << 20));          // 128 KB
  u8*    P8    = (u8*)   (ws + (50u << 20));          // 8 MB (fp8 K copy)

  prep_pt<<<dim3(16, 32), 256, 0, stream>>>(P, wi, Pbf, PbfT, P8, sbv);
  prep_w<<<48, 256, 0, stream>>>(w1, w2, w3, Wp);
  attn_kernel<<<512, 256, 0, stream>>>(P, wi, P8, PbfT, sbv, attnb);
  mlp_kernel<<<1024, 256, 0, stream>>>(Pbf, attnb, Wp, b1, b2, b3, out);
}